// Round 8
// baseline (717.417 us; speedup 1.0000x reference)
//
#include <hip/hip_runtime.h>
#include <hip/hip_bf16.h>

// ================= problem constants =================
#define NNODES 10000
#define EEDGES 160000
#define HD     512
#define OUTD   128
#define NLAYERS 3
#define MP     10112           // NNODES padded to 79*128
#define KTP    10240           // transposed-layout node-dim pad (16*640)

#define ACT_NONE 0
#define ACT_RELU 1
#define ACT_ELU1 2

typedef __attribute__((ext_vector_type(8))) short bf16x8;
typedef __attribute__((ext_vector_type(4))) float f32x4;

__device__ __forceinline__ void gload16(const void* g, void* l) {
  __builtin_amdgcn_global_load_lds(
      (const __attribute__((address_space(1))) void*)g,
      (__attribute__((address_space(3))) void*)l, 16, 0, 0);
}

__device__ __forceinline__ void unp8(uint4 v, float* f) {
  const ushort* u = (const ushort*)&v;
#pragma unroll
  for (int j = 0; j < 8; ++j) f[j] = __uint_as_float(((unsigned)u[j]) << 16);
}

__device__ __forceinline__ ushort f2bu(float f) {
  __hip_bfloat16 h = __float2bfloat16(f);
  return *reinterpret_cast<ushort*>(&h);
}

__device__ __forceinline__ float elu1f(float v) {
  return (v > 0.f) ? (v + 1.0f) : __expf(v);
}

// ================= init: zero cnt/flag/kvf + kT,vT node-pads =================
__global__ __launch_bounds__(256) void init_k(int* cnt, int* flag,
                                              float* kvf, __hip_bfloat16* kT,
                                              __hip_bfloat16* vT) {
  int i = blockIdx.x * 256 + threadIdx.x;
  if (i < 3 * HD * HD) { kvf[i] = 0.f; return; }
  i -= 3 * HD * HD;
  if (i < NNODES) { cnt[i] = 0; return; }
  i -= NNODES;
  if (i == 0) { *flag = 0; return; }
  i -= 1;
  // pads: 512 rows x 120 uints (240 ushorts) x 2 buffers (QKV never writes pads)
  if (i < 512 * 120 * 2) {
    int b = i / (512 * 120);
    int r = (i % (512 * 120)) / 120;
    int c = (i % 120);
    uint* T = (uint*)(b == 0 ? kT : vT);
    T[((long)r * KTP + NNODES) / 2 + c] = 0u;
  }
}

// ================= edge-index width probe (wave-coalesced atomic) =================
__global__ void probe_i64_k(const void* ei, int* flag, int E_) {
  int i = blockIdx.x * blockDim.x + threadIdx.x;
  bool nz = (i < E_) && (((const int*)ei)[2 * i + 1] != 0);
  unsigned long long m = __ballot(nz);
  if ((threadIdx.x & 63) == 0 && m) atomicOr(flag, 1);  // int32 layout detected
}
__device__ inline void load_edge(const void* ei, int is_i32, int e, int E_, int& s, int& d) {
  if (is_i32) { s = ((const int*)ei)[e]; d = ((const int*)ei)[E_ + e]; }
  else { s = (int)((const long long*)ei)[e]; d = (int)((const long long*)ei)[E_ + e]; }
}

// ================= bf16 MFMA GEMM (m97 structure + XCD swizzle) =================
// C = epi(A[M,lda] @ Bt[N,ldb]^T), Bt row-major [N][K].
// 128x128 tile, BK=32, 4 waves (2x2), wave tile 64x64.
// Epilogue: ATOMIC | (scale -> bias -> act -> store).
// TQKV: N=1536 fused q/k/v; LDS-staged coalesced stores:
//   g0: q=elu1 -> Cb row-major; g1: k=elu1 -> kTp[c][node]; g2: v -> vTp[c][node].
template<int ACT, int HAS_BIAS, int HAS_SCALE, int OUTF, int OUTB, int ATOMIC, int TQKV>
__global__ __launch_bounds__(256) void mgemm(
    const __hip_bfloat16* __restrict__ A, const __hip_bfloat16* __restrict__ Bt,
    const float* __restrict__ bias, const float* __restrict__ rowscale,
    float* __restrict__ Cf, __hip_bfloat16* __restrict__ Cb,
    __hip_bfloat16* __restrict__ kTp, __hip_bfloat16* __restrict__ vTp,
    int M, int lda, int ldb, int ldc, int ldcb, int Ksz)
{
  __shared__ __align__(16) __hip_bfloat16 As[128 * 32];
  __shared__ __align__(16) __hip_bfloat16 Bs[128 * 32];
  __shared__ __align__(16) ushort eps[TQKV ? 128 * 136 : 8];

  // bijective XCD-aware swizzle (m204)
  int nwg = gridDim.x * gridDim.y;
  int orig = blockIdx.y * gridDim.x + blockIdx.x;
  int qq = nwg >> 3, rr8 = nwg & 7;
  int xcd = orig & 7, idx = orig >> 3;
  int wg = (xcd < rr8 ? xcd * (qq + 1) : rr8 * (qq + 1) + (xcd - rr8) * qq) + idx;
  int bx = wg % gridDim.x, by = wg / gridDim.x;

  int tid = threadIdx.x;
  int lane = tid & 63;
  int wave = tid >> 6;
  int wm = wave >> 1, wn = wave & 1;
  int row0 = by * 128;
  int col0 = bx * 128;
  int koff = blockIdx.z * Ksz;
  int srow = lane >> 2;
  int sbyte = (lane & 3) * 16;

  f32x4 acc[4][4];
#pragma unroll
  for (int i = 0; i < 4; ++i)
#pragma unroll
    for (int j = 0; j < 4; ++j) acc[i][j] = f32x4{0.f, 0.f, 0.f, 0.f};

  int r16 = lane & 15;
  int kg = (lane >> 4) * 16;

  for (int k0 = koff; k0 < koff + Ksz; k0 += 32) {
#pragma unroll
    for (int j = 0; j < 2; ++j) {
      int c = wave * 2 + j;
      const char* ga = (const char*)(A + (long)(row0 + c * 16 + srow) * lda + k0) + sbyte;
      gload16(ga, (char*)As + c * 1024);
      const char* gb = (const char*)(Bt + (long)(col0 + c * 16 + srow) * ldb + k0) + sbyte;
      gload16(gb, (char*)Bs + c * 1024);
    }
    __syncthreads();
    bf16x8 af[4], bfr[4];
#pragma unroll
    for (int i = 0; i < 4; ++i)
      af[i] = *(const bf16x8*)((const char*)As + (wm * 64 + i * 16 + r16) * 64 + kg);
#pragma unroll
    for (int i = 0; i < 4; ++i)
      bfr[i] = *(const bf16x8*)((const char*)Bs + (wn * 64 + i * 16 + r16) * 64 + kg);
#pragma unroll
    for (int i = 0; i < 4; ++i)
#pragma unroll
      for (int j = 0; j < 4; ++j)
        acc[i][j] = __builtin_amdgcn_mfma_f32_16x16x32_bf16(af[i], bfr[j], acc[i][j], 0, 0, 0);
    __syncthreads();
  }

  // D frag: col = lane&15, row = (lane>>4)*4 + r  [m89/m91-verified]
  int rg = (lane >> 4) * 4;
  if (TQKV) {
    int colg = col0 + wn * 64;
    int g = colg >> 9;                // block-uniform (128-tile within 512-group)
    int cbase = col0 & 511;
    // stage tile into LDS: g0 as [row][136], g1/2 as [c][136]
#pragma unroll
    for (int i = 0; i < 4; ++i) {
#pragma unroll
      for (int j = 0; j < 4; ++j) {
        int c_l = wn * 64 + j * 16 + r16;
        int row_l = wm * 64 + i * 16 + rg;
        if (g == 0) {
#pragma unroll
          for (int r = 0; r < 4; ++r)
            eps[(row_l + r) * 136 + c_l] = f2bu(elu1f(acc[i][j][r]));
        } else {
          ushort4 o;
          o.x = f2bu(g == 1 ? elu1f(acc[i][j][0]) : acc[i][j][0]);
          o.y = f2bu(g == 1 ? elu1f(acc[i][j][1]) : acc[i][j][1]);
          o.z = f2bu(g == 1 ? elu1f(acc[i][j][2]) : acc[i][j][2]);
          o.w = f2bu(g == 1 ? elu1f(acc[i][j][3]) : acc[i][j][3]);
          *(ushort4*)&eps[c_l * 136 + row_l] = o;
        }
      }
    }
    __syncthreads();
    int l16 = tid & 15, cw = tid >> 4;
    if (g == 0) {
#pragma unroll
      for (int rr = cw; rr < 128; rr += 16) {
        int node = row0 + rr;
        if (node < NNODES)
          *(uint4*)((ushort*)Cb + (long)node * ldcb + cbase + l16 * 8) =
              *(const uint4*)&eps[rr * 136 + l16 * 8];
      }
    } else {
      ushort* T = (ushort*)(g == 1 ? kTp : vTp);
      int node0 = row0 + l16 * 8;
      if (node0 < NNODES) {
#pragma unroll
        for (int cc = cw; cc < 128; cc += 16)
          *(uint4*)(T + (long)(cbase + cc) * KTP + node0) = *(const uint4*)&eps[cc * 136 + l16 * 8];
      }
    }
    return;
  }
#pragma unroll
  for (int i = 0; i < 4; ++i) {
#pragma unroll
    for (int j = 0; j < 4; ++j) {
      int col = col0 + wn * 64 + j * 16 + r16;
#pragma unroll
      for (int r = 0; r < 4; ++r) {
        int row = row0 + wm * 64 + i * 16 + rg + r;
        if (row >= M) continue;
        float v = acc[i][j][r];
        if (ATOMIC) { atomicAdd(&Cf[(long)row * ldc + col], v); continue; }
        if (HAS_SCALE) v *= rowscale[row];
        if (HAS_BIAS) v += bias[col];
        if (ACT == ACT_RELU) v = fmaxf(v, 0.f);
        if (ACT == ACT_ELU1) v = elu1f(v);
        if (OUTF) Cf[(long)row * ldc + col] = v;
        if (OUTB) Cb[(long)row * ldcb + col] = __float2bfloat16(v);
      }
    }
  }
}

// ================= weight transpose+cast f32->bf16 =================
// z=0: W_in; z=1..9: {Wq,Wk,Wv} per layer; z=10..12: Wo; z=13: W_gcn;
// z=14/15: W_mix halves -> WMT [512][1024]; z=16: W_cls -> WCT [128][512].
__global__ __launch_bounds__(256) void wtrans_k(
    const float* W_in, const float* Wq, const float* Wk, const float* Wv,
    const float* Wo, const float* W_gcn, const float* W_mix, const float* W_cls,
    __hip_bfloat16* WT, __hip_bfloat16* WMT, __hip_bfloat16* WCT)
{
  int z = blockIdx.z;
  const float* src;
  __hip_bfloat16* out;
  int ldout = 512, koff = 0, ldsrc = 512;
  if (z == 0) { src = W_in; out = WT; }
  else if (z <= 9) {
    int l = (z - 1) / 3, w = (z - 1) % 3;
    src = (w == 0 ? Wq : w == 1 ? Wk : Wv) + (long)l * 262144;
    out = WT + (long)z * 262144;
  } else if (z <= 12) { src = Wo + (long)(z - 10) * 262144; out = WT + (long)z * 262144; }
  else if (z == 13) { src = W_gcn; out = WT + 13L * 262144; }
  else if (z <= 15) { src = W_mix + (long)(z - 14) * 262144; out = WMT; ldout = 1024; koff = (z - 14) * 512; }
  else {
    if (blockIdx.x >= 4) return;      // W_cls has only 128 cols
    src = W_cls; out = WCT; ldsrc = 128;
  }
  __shared__ float t[32][33];
  int r0 = blockIdx.y * 32, c0 = blockIdx.x * 32;
  int tx = threadIdx.x & 31, ty = threadIdx.x >> 5;
#pragma unroll
  for (int i = 0; i < 32; i += 8) t[ty + i][tx] = src[(long)(r0 + ty + i) * ldsrc + c0 + tx];
  __syncthreads();
#pragma unroll
  for (int i = 0; i < 32; i += 8)
    out[(long)(c0 + ty + i) * ldout + koff + r0 + tx] = __float2bfloat16(t[tx][ty + i]);
}

// ================= cast x f32 -> bf16, zero-pad rows to MP =================
__global__ void castx_k(const float* __restrict__ x, __hip_bfloat16* __restrict__ xb) {
  long i = (long)blockIdx.x * 256 + threadIdx.x;
  long base = i * 8;
  if (base >= (long)MP * HD) return;
  int row = (int)(base >> 9);
  ushort o[8];
  if (row < NNODES) {
    float4 a = *(const float4*)(x + base);
    float4 b = *(const float4*)(x + base + 4);
    float f[8] = {a.x, a.y, a.z, a.w, b.x, b.y, b.z, b.w};
#pragma unroll
    for (int j = 0; j < 8; ++j) o[j] = f2bu(f[j]);
  } else {
#pragma unroll
    for (int j = 0; j < 8; ++j) o[j] = 0;
  }
  *(uint4*)((ushort*)xb + base) = *(const uint4*)o;
}

// ====== ksum[i] = rowsum(kT[i][0:NNODES]) — wave per row, no atomics ======
__global__ __launch_bounds__(256) void ksum_k(const __hip_bfloat16* __restrict__ kT,
                                              float* __restrict__ ksum) {
  int i = (blockIdx.x * 256 + threadIdx.x) >> 6;   // 512 rows, grid 128
  int lane = threadIdx.x & 63;
  const ushort* kr = (const ushort*)kT + (long)i * KTP;
  float s = 0.f;
  for (int off = lane * 8; off < NNODES; off += 512) {
    uint4 v = *(const uint4*)(kr + off);
    float f[8]; unp8(v, f);
#pragma unroll
    for (int j = 0; j < 8; ++j) s += f[j];
  }
#pragma unroll
  for (int o = 32; o > 0; o >>= 1) s += __shfl_down(s, o);
  if (lane == 0) ksum[i] = s;
}

// ================= z[n] = 1/max(q.ksum, 1e-6) =================
__global__ __launch_bounds__(256) void z_k(const __hip_bfloat16* __restrict__ qb,
                                           const float* __restrict__ ksum, float* __restrict__ z) {
  long gid = (long)blockIdx.x * 256 + threadIdx.x;
  int row = (int)(gid >> 6), lane = (int)(gid & 63);
  if (row >= NNODES) return;
  uint4 qv = *(const uint4*)((const ushort*)qb + (long)row * HD + lane * 8);
  float f[8]; unp8(qv, f);
  const float* kk = ksum + lane * 8;
  float s = 0.f;
#pragma unroll
  for (int j = 0; j < 8; ++j) s += f[j] * kk[j];
#pragma unroll
  for (int o = 32; o > 0; o >>= 1) s += __shfl_down(s, o);
  if (lane == 0) z[row] = 1.0f / fmaxf(s, 1e-6f);
}

// ================= cast f32 -> bf16 (8/thread) =================
__global__ void cast8_k(const float* __restrict__ s, __hip_bfloat16* __restrict__ d, int n8) {
  int i = blockIdx.x * 256 + threadIdx.x;
  if (i >= n8) return;
  float4 a = ((const float4*)s)[2 * i], b = ((const float4*)s)[2 * i + 1];
  float f[8] = {a.x, a.y, a.z, a.w, b.x, b.y, b.z, b.w};
  ushort o[8];
#pragma unroll
  for (int j = 0; j < 8; ++j) o[j] = f2bu(f[j]);
  *(uint4*)((ushort*)d + (long)i * 8) = *(const uint4*)o;
}

// ====== hg = LN(hg + h[bf16]); f32 -> hg, bf16 -> hgcat[:,0:512] (ld 1024) ======
__global__ __launch_bounds__(256) void ln_res_k(float* __restrict__ hg,
                                                const __hip_bfloat16* __restrict__ hb,
                                                __hip_bfloat16* __restrict__ hgcat) {
  int wid = (blockIdx.x * 256 + threadIdx.x) >> 6;
  int lane = threadIdx.x & 63;
  if (wid >= NNODES) return;
  float* row = hg + (long)wid * HD + lane * 8;
  uint4 hv = *(const uint4*)((const ushort*)hb + (long)wid * HD + lane * 8);
  float hf[8]; unp8(hv, hf);
  float4 p0 = *(const float4*)row, p1 = *(const float4*)(row + 4);
  float a[8] = {p0.x + hf[0], p0.y + hf[1], p0.z + hf[2], p0.w + hf[3],
                p1.x + hf[4], p1.y + hf[5], p1.z + hf[6], p1.w + hf[7]};
  float s = 0.f;
#pragma unroll
  for (int j = 0; j < 8; ++j) s += a[j];
#pragma unroll
  for (int o = 1; o < 64; o <<= 1) s += __shfl_xor(s, o);
  float mean = s * (1.0f / HD);
  float vs = 0.f;
#pragma unroll
  for (int j = 0; j < 8; ++j) { a[j] -= mean; vs += a[j] * a[j]; }
#pragma unroll
  for (int o = 1; o < 64; o <<= 1) vs += __shfl_xor(vs, o);
  float inv = rsqrtf(vs * (1.0f / HD) + 1e-5f);
  ushort ob[8];
#pragma unroll
  for (int j = 0; j < 8; ++j) { a[j] *= inv; ob[j] = f2bu(a[j]); }
  *(float4*)row = make_float4(a[0], a[1], a[2], a[3]);
  *(float4*)(row + 4) = make_float4(a[4], a[5], a[6], a[7]);
  *(uint4*)((ushort*)hgcat + (long)wid * 1024 + lane * 8) = *(const uint4*)ob;
}

// ================= GCN: CSR build + gather =================
__global__ void cnt_k(const void* ei, const int* flag, int* cnt, int E_) {
  int e = blockIdx.x * blockDim.x + threadIdx.x;
  if (e >= E_) return;
  int s, d; load_edge(ei, *flag, e, E_, s, d);
  atomicAdd(&cnt[d], 1);
}
__global__ __launch_bounds__(256) void scan_k(const int* __restrict__ cnt, int* __restrict__ rowptr,
                                              int* __restrict__ cursor, float* __restrict__ dis) {
  __shared__ int ps[256];
  int t = threadIdx.x;
  int lo = t * 40, hi = min(lo + 40, NNODES);
  int s = 0;
  for (int i = lo; i < hi; ++i) s += cnt[i];
  ps[t] = s;
  __syncthreads();
  for (int o = 1; o < 256; o <<= 1) {
    int v = (t >= o) ? ps[t - o] : 0;
    __syncthreads();
    ps[t] += v;
    __syncthreads();
  }
  int run = (t == 0) ? 0 : ps[t - 1];
  for (int i = lo; i < hi; ++i) {
    rowptr[i] = run; cursor[i] = run;
    dis[i] = rsqrtf((float)cnt[i] + 1.0f);
    run += cnt[i];
  }
  if (t == 255) rowptr[NNODES] = run;
}
__global__ void csrfill_k(const void* ei, const int* flag, int* cursor, int* csr, int E_) {
  int e = blockIdx.x * blockDim.x + threadIdx.x;
  if (e >= E_) return;
  int s, d; load_edge(ei, *flag, e, E_, s, d);
  int pos = atomicAdd(&cursor[d], 1);
  csr[pos] = s;
}
// wave per dst: h_graph[d] = relu(sum_src xw[src]*dis[s]*dis[d] + xw[d]*dis[d]^2 + b)
__global__ __launch_bounds__(256) void gcn_gather_k(
    const __hip_bfloat16* __restrict__ xwb, const int* __restrict__ rowptr,
    const int* __restrict__ csr, const float* __restrict__ dis,
    const float* __restrict__ bgcn, __hip_bfloat16* __restrict__ hgcat)
{
  int wid = (blockIdx.x * 256 + threadIdx.x) >> 6;
  int lane = threadIdx.x & 63;
  if (wid >= NNODES) return;
  int d = wid;
  float dd = dis[d];
  float acc[8], f[8], f2[8];
  uint4 v = *(const uint4*)((const ushort*)xwb + (long)d * HD + lane * 8);
  unp8(v, f);
#pragma unroll
  for (int j = 0; j < 8; ++j) acc[j] = f[j] * dd * dd;
  int e0 = rowptr[d], e1 = rowptr[d + 1];
  int e = e0;
  for (; e + 1 < e1; e += 2) {
    int s0 = csr[e], s1 = csr[e + 1];
    float w0 = dis[s0] * dd, w1 = dis[s1] * dd;
    uint4 xv0 = *(const uint4*)((const ushort*)xwb + (long)s0 * HD + lane * 8);
    uint4 xv1 = *(const uint4*)((const ushort*)xwb + (long)s1 * HD + lane * 8);
    unp8(xv0, f); unp8(xv1, f2);
#pragma unroll
    for (int j = 0; j < 8; ++j) acc[j] = fmaf(f[j], w0, fmaf(f2[j], w1, acc[j]));
  }
  if (e < e1) {
    int sN = csr[e];
    float w = dis[sN] * dd;
    uint4 xv = *(const uint4*)((const ushort*)xwb + (long)sN * HD + lane * 8);
    unp8(xv, f);
#pragma unroll
    for (int j = 0; j < 8; ++j) acc[j] = fmaf(f[j], w, acc[j]);
  }
  const float* bb = bgcn + lane * 8;
  ushort o[8];
#pragma unroll
  for (int j = 0; j < 8; ++j) o[j] = f2bu(fmaxf(acc[j] + bb[j], 0.f));
  *(uint4*)((ushort*)hgcat + (long)d * 1024 + 512 + lane * 8) = *(const uint4*)o;
}

// ================= host launcher =================
extern "C" void kernel_launch(void* const* d_in, const int* in_sizes, int n_in,
                              void* d_out, int out_size, void* d_ws, size_t ws_size,
                              hipStream_t stream) {
  const float* x     = (const float*)d_in[0];
  const void*  ei    = d_in[1];
  const float* W_in  = (const float*)d_in[2];
  const float* b_in  = (const float*)d_in[3];
  const float* Wq    = (const float*)d_in[4];
  const float* Wk    = (const float*)d_in[5];
  const float* Wv    = (const float*)d_in[6];
  const float* Wo    = (const float*)d_in[7];
  const float* bo    = (const float*)d_in[8];
  const float* W_gcn = (const float*)d_in[9];
  const float* b_gcn = (const float*)d_in[10];
  const float* W_mix = (const float*)d_in[11];
  const float* b_mix = (const float*)d_in[12];
  const float* W_cls = (const float*)d_in[13];
  const float* b_cls = (const float*)d_in[14];
  float* out = (float*)d_out;

  // ---- workspace layout (~90 MB) ----
  char* p = (char*)d_ws;
  __hip_bfloat16* WT  = (__hip_bfloat16*)p; p += 14L * 262144 * 2;
  __hip_bfloat16* WMT = (__hip_bfloat16*)p; p += 512L * 1024 * 2;
  __hip_bfloat16* WCT = (__hip_bfloat16*)p; p += 128L * 512 * 2;
  float* hg = (float*)p; p += (long)MP * HD * 4;
  __hip_bfloat16* hgcat = (__hip_bfloat16*)p; p += (long)MP * 1024 * 2;
  __hip_bfloat16* qb = (__hip_bfloat16*)p; p += (long)MP * HD * 2;   // xb/xwb alias
  __hip_bfloat16* vT = (__hip_bfloat16*)p; p += 512L * KTP * 2;
  __hip_bfloat16* kT = (__hip_bfloat16*)p; p += 512L * KTP * 2;     // hb/hmixb alias
  float* kvf = (float*)p; p += 3L * 512 * 512 * 4;                   // 3 split-K slots
  __hip_bfloat16* kvb  = (__hip_bfloat16*)p; p += 512L * 512 * 2;
  __hip_bfloat16* kvoT = (__hip_bfloat16*)p; p += 512L * 512 * 2;
  float* ksum = (float*)p; p += 3L * 512 * 4;                        // 3 slots
  float* zb   = (float*)p; p += (long)MP * 4;
  int* cnt    = (int*)p; p += 40000;
  int* rowptr = (int*)p; p += 40016;
  int* cursor = (int*)p; p += 40000;
  float* dis  = (float*)p; p += 40000;
  int* csr    = (int*)p; p += 640000;
  int* flag   = (int*)p; p += 4;

  __hip_bfloat16* xb    = qb;     // input cast (dead after x0 GEMM)
  __hip_bfloat16* xwb   = qb;     // GCN xw (dead after gather)
  __hip_bfloat16* hb    = kT;     // attn h bf16 (kT dead after kv GEMM)
  __hip_bfloat16* hmixb = kT;     // mix out (after last layer)

  dim3 blk(256);
  dim3 gG(4, MP / 128);           // N=512 GEMMs
  dim3 gQKV(12, MP / 128);        // N=1536 fused
  dim3 gKV(4, 4, 16);             // kv split-K=16 x 640
  dim3 gS(4, 4);                  // 512x512 kvoT GEMM
  dim3 gCls(1, MP / 128);

  // ---- setup: single init + weights + input cast + probe ----
  {
    int initN = 3 * HD * HD + NNODES + 1 + 512 * 120 * 2;
    init_k<<<(initN + 255) / 256, blk, 0, stream>>>(cnt, flag, kvf, kT, vT);
  }
  wtrans_k<<<dim3(16, 16, 17), blk, 0, stream>>>(W_in, Wq, Wk, Wv, Wo, W_gcn, W_mix,
                                                 W_cls, WT, WMT, WCT);
  castx_k<<<(int)(((long)MP * HD / 8 + 255) / 256), blk, 0, stream>>>(x, xb);
  probe_i64_k<<<(EEDGES + 255) / 256, 256, 0, stream>>>(ei, flag, EEDGES);

  // x0 = relu(x@W_in+b): f32 -> hg, bf16 -> hgcat[:,0:512]
  mgemm<ACT_RELU, 1, 0, 1, 1, 0, 0><<<gG, blk, 0, stream>>>(
      xb, WT, b_in, nullptr, hg, hgcat, nullptr, nullptr, NNODES, HD, HD, HD, 1024, HD);

  // ---- GCN branch ----
  mgemm<ACT_NONE, 0, 0, 0, 1, 0, 0><<<gG, blk, 0, stream>>>(
      hgcat, WT + 13L * 262144, nullptr, nullptr, nullptr, xwb, nullptr, nullptr,
      NNODES, 1024, HD, HD, HD, HD);
  cnt_k<<<(EEDGES + 255) / 256, 256, 0, stream>>>(ei, flag, cnt, EEDGES);
  scan_k<<<1, 256, 0, stream>>>(cnt, rowptr, cursor, dis);
  csrfill_k<<<(EEDGES + 255) / 256, 256, 0, stream>>>(ei, flag, cursor, csr, EEDGES);
  gcn_gather_k<<<2500, blk, 0, stream>>>(xwb, rowptr, csr, dis, b_gcn, hgcat);

  // ---- attention layers ----
  for (int l = 0; l < NLAYERS; ++l) {
    const __hip_bfloat16* BtQKV = WT + (long)(1 + 3 * l) * 262144;   // [1536][512]
    const __hip_bfloat16* WoT   = WT + (long)(10 + l) * 262144;      // wo^T [512][512]
    float* kvfl  = kvf + (long)l * HD * HD;
    float* ksuml = ksum + (long)l * HD;

    // fused q/k/v: q->qb (elu1), k->kT[c][n] (elu1), v->vT[c][n]
    mgemm<ACT_NONE, 0, 0, 0, 0, 0, 1><<<gQKV, blk, 0, stream>>>(
        hgcat, BtQKV, nullptr, nullptr, nullptr, qb, kT, vT,
        NNODES, 1024, HD, HD, HD, HD);
    ksum_k<<<128, blk, 0, stream>>>(kT, ksuml);

    // kv[i][j] = sum_n k[n][i] v[n][j]  (A=kT, Bt=vT, split-K atomic f32)
    mgemm<ACT_NONE, 0, 0, 0, 0, 1, 0><<<gKV, blk, 0, stream>>>(
        kT, vT, nullptr, nullptr, kvfl, nullptr, nullptr, nullptr,
        HD, KTP, KTP, HD, HD, 640);
    cast8_k<<<128, blk, 0, stream>>>(kvfl, kvb, HD * HD / 8);

    // kvoT[j][i] = sum_m wo[m][j] kv[i][m]  (A=WoT, Bt=kvb)
    mgemm<ACT_NONE, 0, 0, 0, 1, 0, 0><<<gS, blk, 0, stream>>>(
        WoT, kvb, nullptr, nullptr, nullptr, kvoT, nullptr, nullptr,
        HD, HD, HD, HD, HD, HD);

    z_k<<<2500, blk, 0, stream>>>(qb, ksuml, zb);
    // h = (q @ kvo)*z + bo  -> hb bf16
    mgemm<ACT_NONE, 1, 1, 0, 1, 0, 0><<<gG, blk, 0, stream>>>(
        qb, kvoT, bo + (long)l * HD, zb, nullptr, hb, nullptr, nullptr,
        NNODES, HD, HD, HD, HD, HD);
    ln_res_k<<<2500, blk, 0, stream>>>(hg, hb, hgcat);
  }

  // ---- mix (K=1024 over hgcat) + cls ----
  mgemm<ACT_RELU, 1, 0, 0, 1, 0, 0><<<gG, blk, 0, stream>>>(
      hgcat, WMT, b_mix, nullptr, nullptr, hmixb, nullptr, nullptr,
      NNODES, 1024, 1024, HD, HD, 1024);
  mgemm<ACT_NONE, 1, 0, 1, 0, 0, 0><<<gCls, blk, 0, stream>>>(
      hmixb, WCT, b_cls, nullptr, out, nullptr, nullptr, nullptr,
      NNODES, HD, HD, OUTD, OUTD, HD);
}

// Round 9
// 660.348 us; speedup vs baseline: 1.0864x; 1.0864x over previous
//
#include <hip/hip_runtime.h>
#include <hip/hip_bf16.h>

// ================= problem constants =================
#define NNODES 10000
#define EEDGES 160000
#define HD     512
#define OUTD   128
#define NLAYERS 3
#define MP     10112           // NNODES padded to 79*128
#define KTP    10240           // transposed-layout node-dim pad (16*640)

#define ACT_NONE 0
#define ACT_RELU 1
#define ACT_ELU1 2

typedef __attribute__((ext_vector_type(8))) short bf16x8;
typedef __attribute__((ext_vector_type(4))) float f32x4;

__device__ __forceinline__ void gload16(const void* g, void* l) {
  __builtin_amdgcn_global_load_lds(
      (const __attribute__((address_space(1))) void*)g,
      (__attribute__((address_space(3))) void*)l, 16, 0, 0);
}

__device__ __forceinline__ void unp8(uint4 v, float* f) {
  const ushort* u = (const ushort*)&v;
#pragma unroll
  for (int j = 0; j < 8; ++j) f[j] = __uint_as_float(((unsigned)u[j]) << 16);
}

__device__ __forceinline__ ushort f2bu(float f) {
  __hip_bfloat16 h = __float2bfloat16(f);
  return *reinterpret_cast<ushort*>(&h);
}

__device__ __forceinline__ float elu1f(float v) {
  return (v > 0.f) ? (v + 1.0f) : __expf(v);
}

// ================= init: zero cnt/flag/kvf + kT,vT node-pads =================
__global__ __launch_bounds__(256) void init_k(int* cnt, int* flag,
                                              float* kvf, __hip_bfloat16* kT,
                                              __hip_bfloat16* vT) {
  int i = blockIdx.x * 256 + threadIdx.x;
  if (i < 3 * HD * HD) { kvf[i] = 0.f; return; }
  i -= 3 * HD * HD;
  if (i < NNODES) { cnt[i] = 0; return; }
  i -= NNODES;
  if (i == 0) { *flag = 0; return; }
  i -= 1;
  // pads: 512 rows x 120 uints (240 ushorts) x 2 buffers (QKV never writes pads)
  if (i < 512 * 120 * 2) {
    int b = i / (512 * 120);
    int r = (i % (512 * 120)) / 120;
    int c = (i % 120);
    uint* T = (uint*)(b == 0 ? kT : vT);
    T[((long)r * KTP + NNODES) / 2 + c] = 0u;
  }
}

// ================= edge-index width probe (wave-coalesced atomic) =================
__global__ void probe_i64_k(const void* ei, int* flag, int E_) {
  int i = blockIdx.x * blockDim.x + threadIdx.x;
  bool nz = (i < E_) && (((const int*)ei)[2 * i + 1] != 0);
  unsigned long long m = __ballot(nz);
  if ((threadIdx.x & 63) == 0 && m) atomicOr(flag, 1);  // int32 layout detected
}
__device__ inline void load_edge(const void* ei, int is_i32, int e, int E_, int& s, int& d) {
  if (is_i32) { s = ((const int*)ei)[e]; d = ((const int*)ei)[E_ + e]; }
  else { s = (int)((const long long*)ei)[e]; d = (int)((const long long*)ei)[E_ + e]; }
}

// ================= bf16 MFMA GEMM (m97 structure, BK=64, XCD swizzle) =================
// C = epi(A[M,lda] @ Bt[N,ldb]^T), Bt row-major [N][K].
// 128x128 tile, BK=64 (8 iters @ K=512 -> half the barrier drains of BK=32),
// 4 waves (2x2), wave tile 64x64. LDS rows 128B, XOR bank-swizzle applied on
// BOTH sides (pre-swizzled global source + swizzled ds_read) per rule #21.
// TQKV epilogue LDS (eps) UNIONED with As/Bs (dead after final barrier).
template<int ACT, int HAS_BIAS, int HAS_SCALE, int OUTF, int OUTB, int ATOMIC, int TQKV>
__global__ __launch_bounds__(256) void mgemm(
    const __hip_bfloat16* __restrict__ A, const __hip_bfloat16* __restrict__ Bt,
    const float* __restrict__ bias, const float* __restrict__ rowscale,
    float* __restrict__ Cf, __hip_bfloat16* __restrict__ Cb,
    __hip_bfloat16* __restrict__ kTp, __hip_bfloat16* __restrict__ vTp,
    int M, int lda, int ldb, int ldc, int ldcb, int Ksz)
{
  // As: [0,16384) rows 128B; Bs: [16384,32768); TQKV eps overlaps from 0 (34816B)
  __shared__ __align__(16) char smem[TQKV ? 35072 : 32768];

  // bijective XCD-aware swizzle (m204)
  int nwg = gridDim.x * gridDim.y;
  int orig = blockIdx.y * gridDim.x + blockIdx.x;
  int qq = nwg >> 3, rr8 = nwg & 7;
  int xcd = orig & 7, idx = orig >> 3;
  int wg = (xcd < rr8 ? xcd * (qq + 1) : rr8 * (qq + 1) + (xcd - rr8) * qq) + idx;
  int bx = wg % gridDim.x, by = wg / gridDim.x;

  int tid = threadIdx.x;
  int lane = tid & 63;
  int wave = tid >> 6;
  int wm = wave >> 1, wn = wave & 1;
  int row0 = by * 128;
  int col0 = bx * 128;
  int koff = blockIdx.z * Ksz;
  int srow8 = lane >> 3;               // 0..7 (row within 8-row chunk)
  int sb = ((lane & 7) * 16) ^ (srow8 << 4);  // pre-swizzled source byte in 128B row

  f32x4 acc[4][4];
#pragma unroll
  for (int i = 0; i < 4; ++i)
#pragma unroll
    for (int j = 0; j < 4; ++j) acc[i][j] = f32x4{0.f, 0.f, 0.f, 0.f};

  int r16 = lane & 15;
  int kg = (lane >> 4) * 16;           // 16B k-group within 64B half-row
  int rsw = (r16 & 7) << 4;            // read-side XOR (row&7)<<4

  for (int k0 = koff; k0 < koff + Ksz; k0 += 64) {
    // stage A then B: wave w covers rows w*32..w*32+31 in 4 issues of 8 rows.
    // LDS dest wave-uniform; HW adds lane*16 -> row srow8, byte (lane&7)*16.
    // Source byte XOR'd so a swizzled ds_read returns the true data (rule #21).
#pragma unroll
    for (int j = 0; j < 4; ++j) {
      int rbase = wave * 32 + j * 8;
      const char* ga = (const char*)(A + (long)(row0 + rbase + srow8) * lda + k0) + sb;
      gload16(ga, smem + rbase * 128);
      const char* gb = (const char*)(Bt + (long)(col0 + rbase + srow8) * ldb + k0) + sb;
      gload16(gb, smem + 16384 + rbase * 128);
    }
    __syncthreads();
#pragma unroll
    for (int s = 0; s < 2; ++s) {
      bf16x8 af[4], bfr[4];
      int off = ((s * 64 + kg) ^ rsw);
#pragma unroll
      for (int i = 0; i < 4; ++i)
        af[i] = *(const bf16x8*)(smem + (wm * 64 + i * 16 + r16) * 128 + off);
#pragma unroll
      for (int i = 0; i < 4; ++i)
        bfr[i] = *(const bf16x8*)(smem + 16384 + (wn * 64 + i * 16 + r16) * 128 + off);
#pragma unroll
      for (int i = 0; i < 4; ++i)
#pragma unroll
        for (int j = 0; j < 4; ++j)
          acc[i][j] = __builtin_amdgcn_mfma_f32_16x16x32_bf16(af[i], bfr[j], acc[i][j], 0, 0, 0);
    }
    __syncthreads();
  }

  // D frag: col = lane&15, row = (lane>>4)*4 + r  [m89/m91-verified]
  int rg = (lane >> 4) * 4;
  if (TQKV) {
    ushort* eps = (ushort*)smem;      // unions with As/Bs (dead after final barrier)
    int colg = col0 + wn * 64;
    int g = colg >> 9;                // block-uniform (128-tile within 512-group)
    int cbase = col0 & 511;
    // stage tile into LDS: g0 as [row][136], g1/2 as [c][136]
#pragma unroll
    for (int i = 0; i < 4; ++i) {
#pragma unroll
      for (int j = 0; j < 4; ++j) {
        int c_l = wn * 64 + j * 16 + r16;
        int row_l = wm * 64 + i * 16 + rg;
        if (g == 0) {
#pragma unroll
          for (int r = 0; r < 4; ++r)
            eps[(row_l + r) * 136 + c_l] = f2bu(elu1f(acc[i][j][r]));
        } else {
          ushort4 o;
          o.x = f2bu(g == 1 ? elu1f(acc[i][j][0]) : acc[i][j][0]);
          o.y = f2bu(g == 1 ? elu1f(acc[i][j][1]) : acc[i][j][1]);
          o.z = f2bu(g == 1 ? elu1f(acc[i][j][2]) : acc[i][j][2]);
          o.w = f2bu(g == 1 ? elu1f(acc[i][j][3]) : acc[i][j][3]);
          *(ushort4*)&eps[c_l * 136 + row_l] = o;
        }
      }
    }
    __syncthreads();
    int l16 = tid & 15, cw = tid >> 4;
    if (g == 0) {
#pragma unroll
      for (int rr = cw; rr < 128; rr += 16) {
        int node = row0 + rr;
        if (node < NNODES)
          *(uint4*)((ushort*)Cb + (long)node * ldcb + cbase + l16 * 8) =
              *(const uint4*)&eps[rr * 136 + l16 * 8];
      }
    } else {
      ushort* T = (ushort*)(g == 1 ? kTp : vTp);
      int node0 = row0 + l16 * 8;
      if (node0 < NNODES) {
#pragma unroll
        for (int cc = cw; cc < 128; cc += 16)
          *(uint4*)(T + (long)(cbase + cc) * KTP + node0) = *(const uint4*)&eps[cc * 136 + l16 * 8];
      }
    }
    return;
  }
#pragma unroll
  for (int i = 0; i < 4; ++i) {
#pragma unroll
    for (int j = 0; j < 4; ++j) {
      int col = col0 + wn * 64 + j * 16 + r16;
#pragma unroll
      for (int r = 0; r < 4; ++r) {
        int row = row0 + wm * 64 + i * 16 + rg + r;
        if (row >= M) continue;
        float v = acc[i][j][r];
        if (ATOMIC) { atomicAdd(&Cf[(long)row * ldc + col], v); continue; }
        if (HAS_SCALE) v *= rowscale[row];
        if (HAS_BIAS) v += bias[col];
        if (ACT == ACT_RELU) v = fmaxf(v, 0.f);
        if (ACT == ACT_ELU1) v = elu1f(v);
        if (OUTF) Cf[(long)row * ldc + col] = v;
        if (OUTB) Cb[(long)row * ldcb + col] = __float2bfloat16(v);
      }
    }
  }
}

// ================= weight transpose+cast f32->bf16 =================
// z=0: W_in; z=1..9: {Wq,Wk,Wv} per layer; z=10..12: Wo; z=13: W_gcn;
// z=14/15: W_mix halves -> WMT [512][1024]; z=16: W_cls -> WCT [128][512].
__global__ __launch_bounds__(256) void wtrans_k(
    const float* W_in, const float* Wq, const float* Wk, const float* Wv,
    const float* Wo, const float* W_gcn, const float* W_mix, const float* W_cls,
    __hip_bfloat16* WT, __hip_bfloat16* WMT, __hip_bfloat16* WCT)
{
  int z = blockIdx.z;
  const float* src;
  __hip_bfloat16* out;
  int ldout = 512, koff = 0, ldsrc = 512;
  if (z == 0) { src = W_in; out = WT; }
  else if (z <= 9) {
    int l = (z - 1) / 3, w = (z - 1) % 3;
    src = (w == 0 ? Wq : w == 1 ? Wk : Wv) + (long)l * 262144;
    out = WT + (long)z * 262144;
  } else if (z <= 12) { src = Wo + (long)(z - 10) * 262144; out = WT + (long)z * 262144; }
  else if (z == 13) { src = W_gcn; out = WT + 13L * 262144; }
  else if (z <= 15) { src = W_mix + (long)(z - 14) * 262144; out = WMT; ldout = 1024; koff = (z - 14) * 512; }
  else {
    if (blockIdx.x >= 4) return;      // W_cls has only 128 cols
    src = W_cls; out = WCT; ldsrc = 128;
  }
  __shared__ float t[32][33];
  int r0 = blockIdx.y * 32, c0 = blockIdx.x * 32;
  int tx = threadIdx.x & 31, ty = threadIdx.x >> 5;
#pragma unroll
  for (int i = 0; i < 32; i += 8) t[ty + i][tx] = src[(long)(r0 + ty + i) * ldsrc + c0 + tx];
  __syncthreads();
#pragma unroll
  for (int i = 0; i < 32; i += 8)
    out[(long)(c0 + ty + i) * ldout + koff + r0 + tx] = __float2bfloat16(t[tx][ty + i]);
}

// ================= cast x f32 -> bf16, zero-pad rows to MP =================
__global__ void castx_k(const float* __restrict__ x, __hip_bfloat16* __restrict__ xb) {
  long i = (long)blockIdx.x * 256 + threadIdx.x;
  long base = i * 8;
  if (base >= (long)MP * HD) return;
  int row = (int)(base >> 9);
  ushort o[8];
  if (row < NNODES) {
    float4 a = *(const float4*)(x + base);
    float4 b = *(const float4*)(x + base + 4);
    float f[8] = {a.x, a.y, a.z, a.w, b.x, b.y, b.z, b.w};
#pragma unroll
    for (int j = 0; j < 8; ++j) o[j] = f2bu(f[j]);
  } else {
#pragma unroll
    for (int j = 0; j < 8; ++j) o[j] = 0;
  }
  *(uint4*)((ushort*)xb + base) = *(const uint4*)o;
}

// ====== ksum[i] = rowsum(kT[i][0:NNODES]) — wave per row, no atomics ======
__global__ __launch_bounds__(256) void ksum_k(const __hip_bfloat16* __restrict__ kT,
                                              float* __restrict__ ksum) {
  int i = (blockIdx.x * 256 + threadIdx.x) >> 6;   // 512 rows, grid 128
  int lane = threadIdx.x & 63;
  const ushort* kr = (const ushort*)kT + (long)i * KTP;
  float s = 0.f;
  for (int off = lane * 8; off < NNODES; off += 512) {
    uint4 v = *(const uint4*)(kr + off);
    float f[8]; unp8(v, f);
#pragma unroll
    for (int j = 0; j < 8; ++j) s += f[j];
  }
#pragma unroll
  for (int o = 32; o > 0; o >>= 1) s += __shfl_down(s, o);
  if (lane == 0) ksum[i] = s;
}

// ================= z[n] = 1/max(q.ksum, 1e-6) =================
__global__ __launch_bounds__(256) void z_k(const __hip_bfloat16* __restrict__ qb,
                                           const float* __restrict__ ksum, float* __restrict__ z) {
  long gid = (long)blockIdx.x * 256 + threadIdx.x;
  int row = (int)(gid >> 6), lane = (int)(gid & 63);
  if (row >= NNODES) return;
  uint4 qv = *(const uint4*)((const ushort*)qb + (long)row * HD + lane * 8);
  float f[8]; unp8(qv, f);
  const float* kk = ksum + lane * 8;
  float s = 0.f;
#pragma unroll
  for (int j = 0; j < 8; ++j) s += f[j] * kk[j];
#pragma unroll
  for (int o = 32; o > 0; o >>= 1) s += __shfl_down(s, o);
  if (lane == 0) z[row] = 1.0f / fmaxf(s, 1e-6f);
}

// ================= cast f32 -> bf16 (8/thread) =================
__global__ void cast8_k(const float* __restrict__ s, __hip_bfloat16* __restrict__ d, int n8) {
  int i = blockIdx.x * 256 + threadIdx.x;
  if (i >= n8) return;
  float4 a = ((const float4*)s)[2 * i], b = ((const float4*)s)[2 * i + 1];
  float f[8] = {a.x, a.y, a.z, a.w, b.x, b.y, b.z, b.w};
  ushort o[8];
#pragma unroll
  for (int j = 0; j < 8; ++j) o[j] = f2bu(f[j]);
  *(uint4*)((ushort*)d + (long)i * 8) = *(const uint4*)o;
}

// ====== hg = LN(hg + h[bf16]); f32 -> hg, bf16 -> hgcat[:,0:512] (ld 1024) ======
__global__ __launch_bounds__(256) void ln_res_k(float* __restrict__ hg,
                                                const __hip_bfloat16* __restrict__ hb,
                                                __hip_bfloat16* __restrict__ hgcat) {
  int wid = (blockIdx.x * 256 + threadIdx.x) >> 6;
  int lane = threadIdx.x & 63;
  if (wid >= NNODES) return;
  float* row = hg + (long)wid * HD + lane * 8;
  uint4 hv = *(const uint4*)((const ushort*)hb + (long)wid * HD + lane * 8);
  float hf[8]; unp8(hv, hf);
  float4 p0 = *(const float4*)row, p1 = *(const float4*)(row + 4);
  float a[8] = {p0.x + hf[0], p0.y + hf[1], p0.z + hf[2], p0.w + hf[3],
                p1.x + hf[4], p1.y + hf[5], p1.z + hf[6], p1.w + hf[7]};
  float s = 0.f;
#pragma unroll
  for (int j = 0; j < 8; ++j) s += a[j];
#pragma unroll
  for (int o = 1; o < 64; o <<= 1) s += __shfl_xor(s, o);
  float mean = s * (1.0f / HD);
  float vs = 0.f;
#pragma unroll
  for (int j = 0; j < 8; ++j) { a[j] -= mean; vs += a[j] * a[j]; }
#pragma unroll
  for (int o = 1; o < 64; o <<= 1) vs += __shfl_xor(vs, o);
  float inv = rsqrtf(vs * (1.0f / HD) + 1e-5f);
  ushort ob[8];
#pragma unroll
  for (int j = 0; j < 8; ++j) { a[j] *= inv; ob[j] = f2bu(a[j]); }
  *(float4*)row = make_float4(a[0], a[1], a[2], a[3]);
  *(float4*)(row + 4) = make_float4(a[4], a[5], a[6], a[7]);
  *(uint4*)((ushort*)hgcat + (long)wid * 1024 + lane * 8) = *(const uint4*)ob;
}

// ================= GCN: CSR build + gather =================
__global__ void cnt_k(const void* ei, const int* flag, int* cnt, int E_) {
  int e = blockIdx.x * blockDim.x + threadIdx.x;
  if (e >= E_) return;
  int s, d; load_edge(ei, *flag, e, E_, s, d);
  atomicAdd(&cnt[d], 1);
}
__global__ __launch_bounds__(256) void scan_k(const int* __restrict__ cnt, int* __restrict__ rowptr,
                                              int* __restrict__ cursor, float* __restrict__ dis) {
  __shared__ int ps[256];
  int t = threadIdx.x;
  int lo = t * 40, hi = min(lo + 40, NNODES);
  int s = 0;
  for (int i = lo; i < hi; ++i) s += cnt[i];
  ps[t] = s;
  __syncthreads();
  for (int o = 1; o < 256; o <<= 1) {
    int v = (t >= o) ? ps[t - o] : 0;
    __syncthreads();
    ps[t] += v;
    __syncthreads();
  }
  int run = (t == 0) ? 0 : ps[t - 1];
  for (int i = lo; i < hi; ++i) {
    rowptr[i] = run; cursor[i] = run;
    dis[i] = rsqrtf((float)cnt[i] + 1.0f);
    run += cnt[i];
  }
  if (t == 255) rowptr[NNODES] = run;
}
__global__ void csrfill_k(const void* ei, const int* flag, int* cursor, int* csr, int E_) {
  int e = blockIdx.x * blockDim.x + threadIdx.x;
  if (e >= E_) return;
  int s, d; load_edge(ei, *flag, e, E_, s, d);
  int pos = atomicAdd(&cursor[d], 1);
  csr[pos] = s;
}
// wave per dst: h_graph[d] = relu(sum_src xw[src]*dis[s]*dis[d] + xw[d]*dis[d]^2 + b)
__global__ __launch_bounds__(256) void gcn_gather_k(
    const __hip_bfloat16* __restrict__ xwb, const int* __restrict__ rowptr,
    const int* __restrict__ csr, const float* __restrict__ dis,
    const float* __restrict__ bgcn, __hip_bfloat16* __restrict__ hgcat)
{
  int wid = (blockIdx.x * 256 + threadIdx.x) >> 6;
  int lane = threadIdx.x & 63;
  if (wid >= NNODES) return;
  int d = wid;
  float dd = dis[d];
  float acc[8], f[8], f2[8];
  uint4 v = *(const uint4*)((const ushort*)xwb + (long)d * HD + lane * 8);
  unp8(v, f);
#pragma unroll
  for (int j = 0; j < 8; ++j) acc[j] = f[j] * dd * dd;
  int e0 = rowptr[d], e1 = rowptr[d + 1];
  int e = e0;
  for (; e + 1 < e1; e += 2) {
    int s0 = csr[e], s1 = csr[e + 1];
    float w0 = dis[s0] * dd, w1 = dis[s1] * dd;
    uint4 xv0 = *(const uint4*)((const ushort*)xwb + (long)s0 * HD + lane * 8);
    uint4 xv1 = *(const uint4*)((const ushort*)xwb + (long)s1 * HD + lane * 8);
    unp8(xv0, f); unp8(xv1, f2);
#pragma unroll
    for (int j = 0; j < 8; ++j) acc[j] = fmaf(f[j], w0, fmaf(f2[j], w1, acc[j]));
  }
  if (e < e1) {
    int sN = csr[e];
    float w = dis[sN] * dd;
    uint4 xv = *(const uint4*)((const ushort*)xwb + (long)sN * HD + lane * 8);
    unp8(xv, f);
#pragma unroll
    for (int j = 0; j < 8; ++j) acc[j] = fmaf(f[j], w, acc[j]);
  }
  const float* bb = bgcn + lane * 8;
  ushort o[8];
#pragma unroll
  for (int j = 0; j < 8; ++j) o[j] = f2bu(fmaxf(acc[j] + bb[j], 0.f));
  *(uint4*)((ushort*)hgcat + (long)d * 1024 + 512 + lane * 8) = *(const uint4*)o;
}

// ================= host launcher =================
extern "C" void kernel_launch(void* const* d_in, const int* in_sizes, int n_in,
                              void* d_out, int out_size, void* d_ws, size_t ws_size,
                              hipStream_t stream) {
  const float* x     = (const float*)d_in[0];
  const void*  ei    = d_in[1];
  const float* W_in  = (const float*)d_in[2];
  const float* b_in  = (const float*)d_in[3];
  const float* Wq    = (const float*)d_in[4];
  const float* Wk    = (const float*)d_in[5];
  const float* Wv    = (const float*)d_in[6];
  const float* Wo    = (const float*)d_in[7];
  const float* bo    = (const float*)d_in[8];
  const float* W_gcn = (const float*)d_in[9];
  const float* b_gcn = (const float*)d_in[10];
  const float* W_mix = (const float*)d_in[11];
  const float* b_mix = (const float*)d_in[12];
  const float* W_cls = (const float*)d_in[13];
  const float* b_cls = (const float*)d_in[14];
  float* out = (float*)d_out;

  // ---- workspace layout (~90 MB) ----
  char* p = (char*)d_ws;
  __hip_bfloat16* WT  = (__hip_bfloat16*)p; p += 14L * 262144 * 2;
  __hip_bfloat16* WMT = (__hip_bfloat16*)p; p += 512L * 1024 * 2;
  __hip_bfloat16* WCT = (__hip_bfloat16*)p; p += 128L * 512 * 2;
  float* hg = (float*)p; p += (long)MP * HD * 4;
  __hip_bfloat16* hgcat = (__hip_bfloat16*)p; p += (long)MP * 1024 * 2;
  __hip_bfloat16* qb = (__hip_bfloat16*)p; p += (long)MP * HD * 2;   // xb/xwb alias
  __hip_bfloat16* vT = (__hip_bfloat16*)p; p += 512L * KTP * 2;
  __hip_bfloat16* kT = (__hip_bfloat16*)p; p += 512L * KTP * 2;     // hb/hmixb alias
  float* kvf = (float*)p; p += 3L * 512 * 512 * 4;                   // 3 split-K slots
  __hip_bfloat16* kvb  = (__hip_bfloat16*)p; p += 512L * 512 * 2;
  __hip_bfloat16* kvoT = (__hip_bfloat16*)p; p += 512L * 512 * 2;
  float* ksum = (float*)p; p += 3L * 512 * 4;                        // 3 slots
  float* zb   = (float*)p; p += (long)MP * 4;
  int* cnt    = (int*)p; p += 40000;
  int* rowptr = (int*)p; p += 40016;
  int* cursor = (int*)p; p += 40000;
  float* dis  = (float*)p; p += 40000;
  int* csr    = (int*)p; p += 640000;
  int* flag   = (int*)p; p += 4;

  __hip_bfloat16* xb    = qb;     // input cast (dead after x0 GEMM)
  __hip_bfloat16* xwb   = qb;     // GCN xw (dead after gather)
  __hip_bfloat16* hb    = kT;     // attn h bf16 (kT dead after kv GEMM)
  __hip_bfloat16* hmixb = kT;     // mix out (after last layer)

  dim3 blk(256);
  dim3 gG(4, MP / 128);           // N=512 GEMMs
  dim3 gQKV(12, MP / 128);        // N=1536 fused
  dim3 gKV(4, 4, 16);             // kv split-K=16 x 640
  dim3 gS(4, 4);                  // 512x512 kvoT GEMM
  dim3 gCls(1, MP / 128);

  // ---- setup: single init + weights + input cast + probe ----
  {
    int initN = 3 * HD * HD + NNODES + 1 + 512 * 120 * 2;
    init_k<<<(initN + 255) / 256, blk, 0, stream>>>(cnt, flag, kvf, kT, vT);
  }
  wtrans_k<<<dim3(16, 16, 17), blk, 0, stream>>>(W_in, Wq, Wk, Wv, Wo, W_gcn, W_mix,
                                                 W_cls, WT, WMT, WCT);
  castx_k<<<(int)(((long)MP * HD / 8 + 255) / 256), blk, 0, stream>>>(x, xb);
  probe_i64_k<<<(EEDGES + 255) / 256, 256, 0, stream>>>(ei, flag, EEDGES);

  // x0 = relu(x@W_in+b): f32 -> hg, bf16 -> hgcat[:,0:512]
  mgemm<ACT_RELU, 1, 0, 1, 1, 0, 0><<<gG, blk, 0, stream>>>(
      xb, WT, b_in, nullptr, hg, hgcat, nullptr, nullptr, NNODES, HD, HD, HD, 1024, HD);

  // ---- GCN branch ----
  mgemm<ACT_NONE, 0, 0, 0, 1, 0, 0><<<gG, blk, 0, stream>>>(
      hgcat, WT + 13L * 262144, nullptr, nullptr, nullptr, xwb, nullptr, nullptr,
      NNODES, 1024, HD, HD, HD, HD);
  cnt_k<<<(EEDGES + 255) / 256, 256, 0, stream>>>(ei, flag, cnt, EEDGES);
  scan_k<<<1, 256, 0, stream>>>(cnt, rowptr, cursor, dis);
  csrfill_k<<<(EEDGES + 255) / 256, 256, 0, stream>>>(ei, flag, cursor, csr, EEDGES);
  gcn_gather_k<<<2500, blk, 0, stream>>>(xwb, rowptr, csr, dis, b_gcn, hgcat);

  // ---- attention layers ----
  for (int l = 0; l < NLAYERS; ++l) {
    const __hip_bfloat16* BtQKV = WT + (long)(1 + 3 * l) * 262144;   // [1536][512]
    const __hip_bfloat16* WoT   = WT + (long)(10 + l) * 262144;      // wo^T [512][512]
    float* kvfl  = kvf + (long)l * HD * HD;
    float* ksuml = ksum + (long)l * HD;

    // fused q/k/v: q->qb (elu1), k->kT[c][n] (elu1), v->vT[c][n]
    mgemm<ACT_NONE, 0, 0, 0, 0, 0, 1><<<gQKV, blk, 0, stream>>>(
        hgcat, BtQKV, nullptr, nullptr, nullptr, qb, kT, vT,
        NNODES, 1024, HD, HD, HD, HD);
    ksum_k<<<128, blk, 0, stream>>>(kT, ksuml);

    // kv[i][j] = sum_n k[n][i] v[n][j]  (A=kT, Bt=vT, split-K atomic f32)
    mgemm<ACT_NONE, 0, 0, 0, 0, 1, 0><<<gKV, blk, 0, stream>>>(
        kT, vT, nullptr, nullptr, kvfl, nullptr, nullptr, nullptr,
        HD, KTP, KTP, HD, HD, 640);
    cast8_k<<<128, blk, 0, stream>>>(kvfl, kvb, HD * HD / 8);

    // kvoT[j][i] = sum_m wo[m][j] kv[i][m]  (A=WoT, Bt=kvb)
    mgemm<ACT_NONE, 0, 0, 0, 1, 0, 0><<<gS, blk, 0, stream>>>(
        WoT, kvb, nullptr, nullptr, nullptr, kvoT, nullptr, nullptr,
        HD, HD, HD, HD, HD, HD);

    z_k<<<2500, blk, 0, stream>>>(qb, ksuml, zb);
    // h = (q @ kvo)*z + bo  -> hb bf16
    mgemm<ACT_NONE, 1, 1, 0, 1, 0, 0><<<gG, blk, 0, stream>>>(
        qb, kvoT, bo + (long)l * HD, zb, nullptr, hb, nullptr, nullptr,
        NNODES, HD, HD, HD, HD, HD);
    ln_res_k<<<2500, blk, 0, stream>>>(hg, hb, hgcat);
  }

  // ---- mix (K=1024 over hgcat) + cls ----
  mgemm<ACT_RELU, 1, 0, 0, 1, 0, 0><<<gG, blk, 0, stream>>>(
      hgcat, WMT, b_mix, nullptr, nullptr, hmixb, nullptr, nullptr,
      NNODES, 1024, 1024, HD, HD, 1024);
  mgemm<ACT_NONE, 1, 0, 1, 0, 0, 0><<<gCls, blk, 0, stream>>>(
      hmixb, WCT, b_cls, nullptr, out, nullptr, nullptr, nullptr,
      NNODES, HD, HD, OUTD, OUTD, HD);
}